// Round 9
// baseline (761.694 us; speedup 1.0000x reference)
//
#include <hip/hip_runtime.h>

#define B_ 2
#define S_ 2048
#define D_ 1024      // D_IN = DKQ = DV = E
#define H_ 16
#define HD_ 64       // DV / H

typedef _Float16 f16;
typedef _Float16 half8 __attribute__((ext_vector_type(8)));
typedef float float4_ __attribute__((ext_vector_type(4)));

#define N_HS (B_*S_*D_)   // 4194304
#define N_W  (D_*D_)      // 1048576
#define N_MIX (H_*D_)     // 16384

__device__ __forceinline__ void gl_lds16(const f16* g, const f16* l) {
  __builtin_amdgcn_global_load_lds(
      (const __attribute__((address_space(1))) void*)g,
      (__attribute__((address_space(3))) void*)l, 16, 0, 0);
}

// counted wait + raw barrier (T3+T4).  __syncthreads would drain vmcnt(0).
// In-order vmem completion makes vmcnt(8) correct independent of how the
// compiler interleaves tail loads with the DMA batch (see schedule note).
#define VM_WAIT8()  asm volatile("s_waitcnt vmcnt(8)" ::: "memory")
#define LGKM0()     asm volatile("s_waitcnt lgkmcnt(0)" ::: "memory")
#define RAW_BAR()   asm volatile("s_barrier" ::: "memory")

// ---------------- convert fp32 -> fp16 ----------------
// mixing scaled by (1/sqrt(64)) * (1/ln2): softmax exp becomes a bare exp2
#define MIX_SCALE 0.18033688011112042f

__global__ __launch_bounds__(256) void convert_kernel(
    const float* __restrict__ hs, const float* __restrict__ wq,
    const float* __restrict__ wk, const float* __restrict__ wv,
    const float* __restrict__ mix,
    f16* __restrict__ hs16, f16* __restrict__ wq16, f16* __restrict__ wk16,
    f16* __restrict__ wv16, f16* __restrict__ mix16)
{
  const int total4 = (N_HS + 3*N_W + N_MIX) / 4;
  for (int i4 = blockIdx.x*blockDim.x + threadIdx.x; i4 < total4;
       i4 += gridDim.x*blockDim.x) {
    int i = i4*4;
    const float* src; f16* dst; float scale = 1.0f; int off;
    if (i < N_HS)            { src=hs;  dst=hs16;  off=i; }
    else if (i < N_HS+N_W)   { src=wq;  dst=wq16;  off=i-N_HS; }
    else if (i < N_HS+2*N_W) { src=wk;  dst=wk16;  off=i-N_HS-N_W; }
    else if (i < N_HS+3*N_W) { src=wv;  dst=wv16;  off=i-N_HS-2*N_W; }
    else                     { src=mix; dst=mix16; off=i-N_HS-3*N_W; scale=MIX_SCALE; }
    float4 v = *(const float4*)(src+off);
    dst[off]   = (f16)(v.x*scale);
    dst[off+1] = (f16)(v.y*scale);
    dst[off+2] = (f16)(v.z*scale);
    dst[off+3] = (f16)(v.w*scale);
  }
}

// ---------------- QKV GEMM: 128x128 tiles, DMA staging (m97-style) ----------------
// z==2 (V) adds bias and writes TRANSPOSED: vT[b][ch][t]
// Epilogue: C-tile staged in LDS (transposed for z==2), then coalesced 16B
// float4 stores (R7: killed the vT 2-byte-scatter write amplification).
#define BM 128
#define BN 128
#define BK 64
#define LDC 136   // C-tile pad: keeps 16B alignment (136*2=272=16*17), ~2-way banks

__global__ __launch_bounds__(256, 2) void qkv_kernel(
    const f16* __restrict__ hs16, const f16* __restrict__ w16base,
    const float* __restrict__ bv,
    f16* __restrict__ q16, f16* __restrict__ k16, f16* __restrict__ vT)
{
  const int z = blockIdx.z;
  const f16* W = w16base + (size_t)z * N_W;
  f16* out = (z==0) ? q16 : k16;
  const int mt = blockIdx.y, nt = blockIdx.x;
  const int tid = threadIdx.x;
  const int lane = tid & 63, wid = tid >> 6;
  const int wm = wid >> 1, wn = wid & 1;
  const int quad = lane >> 4, l16 = lane & 15;

  __shared__ __align__(16) union {
    struct { f16 As[BM*BK]; f16 Bs[BN*BK]; } s;  // 32 KB
    f16 Cs[BM*LDC];                              // 34816 B (epilogue staging)
  } u;

  float4_ acc[4][4];
#pragma unroll
  for (int i=0;i<4;i++)
#pragma unroll
    for (int j=0;j<4;j++) acc[i][j] = (float4_)0.0f;

  const int row0 = mt*BM;
  const int col0 = nt*BN;

  for (int ko = 0; ko < D_; ko += BK) {
#pragma unroll
    for (int c=0; c<4; c++) {
      int slot = (wid*4+c)*64 + lane;      // 0..1023 16B chunks
      int r = slot >> 3;
      int gc = (slot & 7) ^ (r & 7);
      gl_lds16(hs16 + (size_t)(row0+r)*D_ + ko + gc*8, u.s.As + (size_t)(wid*4+c)*64*8);
      gl_lds16(W    + (size_t)(col0+r)*D_ + ko + gc*8, u.s.Bs + (size_t)(wid*4+c)*64*8);
    }
    __syncthreads();
#pragma unroll
    for (int kk=0; kk<BK; kk+=32) {
      int ck = (kk >> 3) + quad;
      half8 a[4], b[4];
#pragma unroll
      for (int i=0;i<4;i++) {
        int rr = wm*64 + i*16 + l16;
        a[i] = *(const half8*)&u.s.As[(size_t)(((rr<<3) | (ck ^ (rr&7))) << 3)];
      }
#pragma unroll
      for (int j=0;j<4;j++) {
        int rr = wn*64 + j*16 + l16;
        b[j] = *(const half8*)&u.s.Bs[(size_t)(((rr<<3) | (ck ^ (rr&7))) << 3)];
      }
#pragma unroll
      for (int i=0;i<4;i++)
#pragma unroll
        for (int j=0;j<4;j++)
          acc[i][j] = __builtin_amdgcn_mfma_f32_16x16x32_f16(a[i], b[j], acc[i][j], 0,0,0);
    }
    __syncthreads();
  }

  // ---- epilogue: LDS-staged coalesced stores ----
#pragma unroll
  for (int i=0;i<4;i++) {
#pragma unroll
    for (int j=0;j<4;j++) {
      int c = wn*64 + j*16 + l16;
      float bias = (z==2) ? bv[col0 + c] : 0.0f;
#pragma unroll
      for (int r=0;r<4;r++) {
        int rr = wm*64 + i*16 + quad*4 + r;
        f16 val = (f16)(acc[i][j][r] + bias);
        u.Cs[(z==2) ? ((size_t)c*LDC + rr) : ((size_t)rr*LDC + c)] = val;
      }
    }
  }
  __syncthreads();
  {
    const int c = tid >> 1, half = tid & 1;   // c: tile-major index 0..127
    const f16* srcp = &u.Cs[(size_t)c*LDC + half*64];
    f16* dst;
    if (z == 2) {
      int bb = row0 >> 11, ss0 = (row0 & (S_-1)) + half*64;
      dst = vT + ((size_t)bb*D_ + col0 + c)*S_ + ss0;
    } else {
      dst = out + (size_t)(row0 + c)*D_ + col0 + half*64;
    }
#pragma unroll
    for (int k=0;k<8;k++)
      *(float4*)(dst + k*8) = *(const float4*)(srcp + k*8);
  }
}

// ---------------- flash attention: counted-vmcnt k-pair double buffer ----------------
// R8 core (q VALU staging, setprio, swapped-PV) + the one schedule that meets
// all constraints from R1-R6 post-mortems (no reg-held prefetch, no
// __syncthreads vmcnt(0) drains, no sched fences, no ordering-sensitive
// counted loads):
//   k-pair double buffer: pair_i -> slots {2*(i&1), 2*(i&1)+1}.
//   tail_i (AFTER the post-MFMA raw barrier): stage q_{i+1} (VALU, transient),
//     then DMA pair_{i+2} into the slots pair_i just vacated.
//   head_i: vmcnt(8) waits pair_i (issued at tail_{i-2}, ~1 full iteration of
//     cover).  In-order vmem completion => vmcnt(8) is correct regardless of
//     compiler interleave of tail q-loads with the DMA batch.
//   lgkmcnt(0) + raw s_barrier (never an implicit vmcnt(0) drain).
//   tail_14 DMAs next-t0 pair_0 into slots 0-1 (disjoint from P) -> it rides
//   through the whole PV phase; pair_1 issues in the t0 prologue after the
//   post-PV barrier (slots 2-3 = P region free only then).
// LDS: k[4][16KB] + q[16KB chunked] = 80KB exactly -> 2 blocks/CU (160KB).
// P [128][136] aliases slots 2-3 + 2KB of q; red_l aliases k[0].
#define TQ 128
#define TK 128
#define LDP 136

__global__ __launch_bounds__(256, 2) void attn_kernel(
    const f16* __restrict__ q16, const f16* __restrict__ k16,
    const f16* __restrict__ vT, const f16* __restrict__ mix16,
    float* __restrict__ out)
{
  const int b = blockIdx.z;
  const int h = blockIdx.y;
  const int s0 = blockIdx.x * TQ;
  const int tid = threadIdx.x;
  const int lane = tid & 63, wid = tid >> 6;
  const int wm = wid >> 1, wn = wid & 1;
  const int quad = lane >> 4, l16 = lane & 15;

  __shared__ __align__(16) union {
    struct { f16 k[4][TK*BK]; f16 q[TQ*BK]; } s;      // 64KB + 16KB = 81920 B
    struct { f16 _pad[2*TK*BK]; f16 P[TQ][LDP]; } p;  // P at slots 2-3 (+2KB of q)
    struct { float red_l[2][TQ]; } r;                 // epilogue, aliases k[0]
  } u;

  float l_lane[16];
#pragma unroll
  for (int t=0;t<16;t++) l_lane[t] = 0.0f;

  // o_acc[i][j][r] = O[q_row = wm*64+i*16+l16][d = wn*32+j*16+quad*4+r]  (swapped PV)
  float4_ o_acc[4][2];
#pragma unroll
  for (int i=0;i<4;i++)
#pragma unroll
    for (int j=0;j<2;j++) o_acc[i][j] = (float4_)0.0f;

  const f16* qbase = q16 + (size_t)(b*S_ + s0)*D_;
  const f16* kbase = k16 + (size_t)b*S_*D_;
  const f16* mrow  = mix16 + h*D_;
  const f16* vTb   = vT + (size_t)(b*D_ + h*HD_)*S_;

  // one k-tile pair (t0g, t0g+TK rows at k-slice ko_): 8 DMA instrs/thread
#define STAGE_PAIR(pr, t0g, ko_) do {                                        \
    const f16* k0g_ = kbase + (size_t)(t0g)*D_ + (ko_);                      \
    const f16* k1g_ = k0g_ + (size_t)TK*D_;                                  \
    _Pragma("unroll")                                                        \
    for (int c_=0; c_<4; c_++) {                                             \
      int slot_ = (wid*4+c_)*64 + lane;                                      \
      int r_ = slot_ >> 3;                                                   \
      int gc_ = (slot_ & 7) ^ (r_ & 7);                                      \
      gl_lds16(k0g_ + (size_t)r_*D_ + gc_*8, u.s.k[2*(pr)]   + (size_t)(wid*4+c_)*64*8); \
      gl_lds16(k1g_ + (size_t)r_*D_ + gc_*8, u.s.k[2*(pr)+1] + (size_t)(wid*4+c_)*64*8); \
    } } while (0)

  // q staging: transient VALU (load, fuse mix, ds_write to xor-chunked layout)
#define QSTAGE(ko_) do {                                                     \
    _Pragma("unroll")                                                        \
    for (int it_=0; it_<4; it_++) {                                          \
      int c_ = it_*256 + tid; int r_ = c_>>3; int cc_ = c_&7;                \
      half8 qv_ = *(const half8*)&qbase[(size_t)r_*D_ + (ko_) + cc_*8];      \
      half8 mv_ = *(const half8*)&mrow[(ko_) + cc_*8];                       \
      *(half8*)&u.s.q[(size_t)(((r_<<3) | (cc_ ^ (r_&7))) << 3)] = qv_ * mv_; \
    } } while (0)

  STAGE_PAIR(0, 0, 0);   // kernel prologue: pair_0 -> slots 0-1

  for (int t0 = 0; t0 < S_; t0 += 2*TK) {
    const bool has_next = (t0 + 2*TK < S_);

    // t0 prologue (post-PV barrier passed: slots 2-3 and q free)
    QSTAGE(0);
    STAGE_PAIR(1, t0, BK);            // pair_1 -> slots 2-3

    float4_ sacc[2][4][4];
#pragma unroll
    for (int tt=0;tt<2;tt++)
#pragma unroll
      for (int i=0;i<4;i++)
#pragma unroll
        for (int j=0;j<4;j++) sacc[tt][i][j] = (float4_)0.0f;

#pragma unroll 2
    for (int ko_i = 0; ko_i < D_/BK; ko_i++) {
      const int ko = ko_i * BK;
      const int cur = ko_i & 1;

      VM_WAIT8();    // pair_i resident; pair_{i+1} (8 instrs) stays in flight
      LGKM0();       // q_i ds_writes visible
      RAW_BAR();

      __builtin_amdgcn_s_setprio(1);
#pragma unroll
      for (int kk2=0; kk2<2; kk2++) {
        const int ck = kk2*4 + quad;
        half8 a[4];
#pragma unroll
        for (int i=0;i<4;i++) {
          int rr = wm*64 + i*16 + l16;
          a[i] = *(const half8*)&u.s.q[(size_t)(((rr<<3) | (ck ^ (rr&7))) << 3)];
        }
#pragma unroll
        for (int tt=0;tt<2;tt++) {
          const f16* kb = u.s.k[2*cur + tt];
          half8 bf[4];
#pragma unroll
          for (int j=0;j<4;j++) {
            int rr = wn*64 + j*16 + l16;
            bf[j] = *(const half8*)&kb[(size_t)(((rr<<3) | (ck ^ (rr&7))) << 3)];
          }
#pragma unroll
          for (int i=0;i<4;i++)
#pragma unroll
            for (int j=0;j<4;j++)
              sacc[tt][i][j] = __builtin_amdgcn_mfma_f32_16x16x32_f16(a[i], bf[j], sacc[tt][i][j], 0,0,0);
        }
      }
      __builtin_amdgcn_s_setprio(0);

      RAW_BAR();     // all reads of pair_i & q_i retired -> safe to overwrite

      if (ko_i < 14) {
        QSTAGE(ko + BK);                        // q_{i+1} (transient regs only)
        STAGE_PAIR(cur, t0, ko + 2*BK);         // pair_{i+2} -> freed slots
      } else if (ko_i == 14) {
        QSTAGE(ko + BK);                        // q_15
        if (has_next) STAGE_PAIR(0, t0 + 2*TK, 0);   // next-t0 pair_0 -> slots 0-1
      }
      // ko_i == 15: nothing (PV follows; P uses slots 2-3 + q tail)
    }

    // ---- per sub-tile: P = exp2(S), l partials, P->LDS, PV (swapped) ----
#pragma unroll
    for (int tt=0;tt<2;tt++) {
#pragma unroll
      for (int i=0;i<4;i++)
#pragma unroll
        for (int j=0;j<4;j++)
#pragma unroll
          for (int r=0;r<4;r++) {
            float p = __builtin_exp2f(sacc[tt][i][j][r]);
            l_lane[i*4+r] += p;
            u.p.P[wm*64+i*16+quad*4+r][wn*64+j*16+l16] = (f16)p;
          }

      // prefetch PV fragments (latency hides under barrier; transient regs)
      half8 vb[8];
#pragma unroll
      for (int ki=0; ki<4; ki++)
#pragma unroll
        for (int j=0; j<2; j++) {
          int ch = wn*32 + j*16 + l16;
          vb[ki*2+j] = *(const half8*)&vTb[(size_t)ch*S_ + t0 + tt*TK + ki*32 + quad*8];
        }

      LGKM0();       // P visible to all waves
      RAW_BAR();     // raw: next-t0 pair_0 DMA stays in flight

      __builtin_amdgcn_s_setprio(1);
#pragma unroll
      for (int ki=0; ki<4; ki++) {
        half8 pa[4];
#pragma unroll
        for (int i=0;i<4;i++) pa[i] = *(const half8*)&u.p.P[wm*64+i*16+l16][ki*32+quad*8];
#pragma unroll
        for (int i=0;i<4;i++)
#pragma unroll
          for (int j=0;j<2;j++)
            o_acc[i][j] = __builtin_amdgcn_mfma_f32_16x16x32_f16(vb[ki*2+j], pa[i], o_acc[i][j], 0,0,0);
      }
      __builtin_amdgcn_s_setprio(0);
      RAW_BAR();     // P reads retired -> tt1 / next-t0 may overwrite
    }
  }

  // ---- epilogue: single l reduction (butterfly over l16, cross-wave via LDS) ----
#pragma unroll
  for (int d=1; d<16; d<<=1)
#pragma unroll
    for (int t=0;t<16;t++) l_lane[t] += __shfl_xor(l_lane[t], d);
  if (l16 == 0) {
#pragma unroll
    for (int i=0;i<4;i++)
#pragma unroll
      for (int r=0;r<4;r++)
        u.r.red_l[wn][wm*64+i*16+quad*4+r] = l_lane[i*4+r];
  }
  __syncthreads();

  // swapped-PV epilogue: lane holds 4 consecutive d for q_row = wm*64+i*16+l16
#pragma unroll
  for (int i=0;i<4;i++) {
    int row = wm*64 + i*16 + l16;
    float linv = 1.0f / (u.r.red_l[0][row] + u.r.red_l[1][row]);
#pragma unroll
    for (int j=0;j<2;j++) {
      float4 v4;
      v4.x = o_acc[i][j][0] * linv;
      v4.y = o_acc[i][j][1] * linv;
      v4.z = o_acc[i][j][2] * linv;
      v4.w = o_acc[i][j][3] * linv;
      *(float4*)&out[(size_t)(b*S_ + s0 + row)*D_ + h*HD_ + wn*32 + j*16 + quad*4] = v4;
    }
  }
}

// ---------------- launch ----------------
extern "C" void kernel_launch(void* const* d_in, const int* in_sizes, int n_in,
                              void* d_out, int out_size, void* d_ws, size_t ws_size,
                              hipStream_t stream) {
  (void)in_sizes; (void)n_in; (void)out_size; (void)ws_size;
  const float* hs  = (const float*)d_in[0];
  const float* Wq  = (const float*)d_in[1];
  const float* Wk  = (const float*)d_in[2];
  const float* Wv  = (const float*)d_in[3];
  const float* bv  = (const float*)d_in[4];
  const float* mix = (const float*)d_in[5];
  float* out = (float*)d_out;

  char* ws = (char*)d_ws;
  f16* hs16  = (f16*)(ws);                       // 8 MB
  f16* w16   = (f16*)(ws + 8388608);             // 6 MB
  f16* mix16 = (f16*)(ws + 14680064);            // 32 KB
  f16* q16   = (f16*)(ws + 14712832);            // 8 MB
  f16* k16   = (f16*)(ws + 23101440);            // 8 MB
  f16* vT    = (f16*)(ws + 31490048);            // 8 MB

  convert_kernel<<<2048, 256, 0, stream>>>(hs, Wq, Wk, Wv, mix,
                                           hs16, w16, w16+N_W, w16+2*N_W, mix16);
  qkv_kernel<<<dim3(D_/BN, (B_*S_)/BM, 3), 256, 0, stream>>>(
      hs16, w16, bv, q16, k16, vT);
  attn_kernel<<<dim3(S_/TQ, H_, B_), 256, 0, stream>>>(
      q16, k16, vT, mix16, out);
}

// Round 10
// 591.039 us; speedup vs baseline: 1.2887x; 1.2887x over previous
//
#include <hip/hip_runtime.h>

#define B_ 2
#define S_ 2048
#define D_ 1024      // D_IN = DKQ = DV = E
#define H_ 16
#define HD_ 64       // DV / H

typedef _Float16 f16;
typedef _Float16 half8 __attribute__((ext_vector_type(8)));
typedef float float4_ __attribute__((ext_vector_type(4)));

#define N_HS (B_*S_*D_)   // 4194304
#define N_W  (D_*D_)      // 1048576
#define N_MIX (H_*D_)     // 16384

__device__ __forceinline__ void gl_lds16(const f16* g, const f16* l) {
  __builtin_amdgcn_global_load_lds(
      (const __attribute__((address_space(1))) void*)g,
      (__attribute__((address_space(3))) void*)l, 16, 0, 0);
}

// ---------------- convert fp32 -> fp16 ----------------
// mixing scaled by (1/sqrt(64)) * (1/ln2): softmax exp becomes a bare exp2
#define MIX_SCALE 0.18033688011112042f

__global__ __launch_bounds__(256) void convert_kernel(
    const float* __restrict__ hs, const float* __restrict__ wq,
    const float* __restrict__ wk, const float* __restrict__ wv,
    const float* __restrict__ mix,
    f16* __restrict__ hs16, f16* __restrict__ wq16, f16* __restrict__ wk16,
    f16* __restrict__ wv16, f16* __restrict__ mix16)
{
  const int total4 = (N_HS + 3*N_W + N_MIX) / 4;
  for (int i4 = blockIdx.x*blockDim.x + threadIdx.x; i4 < total4;
       i4 += gridDim.x*blockDim.x) {
    int i = i4*4;
    const float* src; f16* dst; float scale = 1.0f; int off;
    if (i < N_HS)            { src=hs;  dst=hs16;  off=i; }
    else if (i < N_HS+N_W)   { src=wq;  dst=wq16;  off=i-N_HS; }
    else if (i < N_HS+2*N_W) { src=wk;  dst=wk16;  off=i-N_HS-N_W; }
    else if (i < N_HS+3*N_W) { src=wv;  dst=wv16;  off=i-N_HS-2*N_W; }
    else                     { src=mix; dst=mix16; off=i-N_HS-3*N_W; scale=MIX_SCALE; }
    float4 v = *(const float4*)(src+off);
    dst[off]   = (f16)(v.x*scale);
    dst[off+1] = (f16)(v.y*scale);
    dst[off+2] = (f16)(v.z*scale);
    dst[off+3] = (f16)(v.w*scale);
  }
}

// ---------------- QKV GEMM: 128x128 tiles, DMA staging (m97-style) ----------------
// z==2 (V) adds bias and writes TRANSPOSED: vT[b][ch][t]
// Epilogue: C-tile staged in LDS (transposed for z==2), then coalesced 16B
// float4 stores (R7: killed the vT 2-byte-scatter write amplification).
#define BM 128
#define BN 128
#define BK 64
#define LDC 136   // C-tile pad: keeps 16B alignment (136*2=272=16*17), ~2-way banks

__global__ __launch_bounds__(256, 2) void qkv_kernel(
    const f16* __restrict__ hs16, const f16* __restrict__ w16base,
    const float* __restrict__ bv,
    f16* __restrict__ q16, f16* __restrict__ k16, f16* __restrict__ vT)
{
  const int z = blockIdx.z;
  const f16* W = w16base + (size_t)z * N_W;
  f16* out = (z==0) ? q16 : k16;
  const int mt = blockIdx.y, nt = blockIdx.x;
  const int tid = threadIdx.x;
  const int lane = tid & 63, wid = tid >> 6;
  const int wm = wid >> 1, wn = wid & 1;
  const int quad = lane >> 4, l16 = lane & 15;

  __shared__ __align__(16) union {
    struct { f16 As[BM*BK]; f16 Bs[BN*BK]; } s;  // 32 KB
    f16 Cs[BM*LDC];                              // 34816 B (epilogue staging)
  } u;

  float4_ acc[4][4];
#pragma unroll
  for (int i=0;i<4;i++)
#pragma unroll
    for (int j=0;j<4;j++) acc[i][j] = (float4_)0.0f;

  const int row0 = mt*BM;
  const int col0 = nt*BN;

  for (int ko = 0; ko < D_; ko += BK) {
#pragma unroll
    for (int c=0; c<4; c++) {
      int slot = (wid*4+c)*64 + lane;      // 0..1023 16B chunks
      int r = slot >> 3;
      int gc = (slot & 7) ^ (r & 7);
      gl_lds16(hs16 + (size_t)(row0+r)*D_ + ko + gc*8, u.s.As + (size_t)(wid*4+c)*64*8);
      gl_lds16(W    + (size_t)(col0+r)*D_ + ko + gc*8, u.s.Bs + (size_t)(wid*4+c)*64*8);
    }
    __syncthreads();
#pragma unroll
    for (int kk=0; kk<BK; kk+=32) {
      int ck = (kk >> 3) + quad;
      half8 a[4], b[4];
#pragma unroll
      for (int i=0;i<4;i++) {
        int rr = wm*64 + i*16 + l16;
        a[i] = *(const half8*)&u.s.As[(size_t)(((rr<<3) | (ck ^ (rr&7))) << 3)];
      }
#pragma unroll
      for (int j=0;j<4;j++) {
        int rr = wn*64 + j*16 + l16;
        b[j] = *(const half8*)&u.s.Bs[(size_t)(((rr<<3) | (ck ^ (rr&7))) << 3)];
      }
#pragma unroll
      for (int i=0;i<4;i++)
#pragma unroll
        for (int j=0;j<4;j++)
          acc[i][j] = __builtin_amdgcn_mfma_f32_16x16x32_f16(a[i], b[j], acc[i][j], 0,0,0);
    }
    __syncthreads();
  }

  // ---- epilogue: LDS-staged coalesced stores ----
#pragma unroll
  for (int i=0;i<4;i++) {
#pragma unroll
    for (int j=0;j<4;j++) {
      int c = wn*64 + j*16 + l16;
      float bias = (z==2) ? bv[col0 + c] : 0.0f;
#pragma unroll
      for (int r=0;r<4;r++) {
        int rr = wm*64 + i*16 + quad*4 + r;
        f16 val = (f16)(acc[i][j][r] + bias);
        u.Cs[(z==2) ? ((size_t)c*LDC + rr) : ((size_t)rr*LDC + c)] = val;
      }
    }
  }
  __syncthreads();
  {
    const int c = tid >> 1, half = tid & 1;   // c: tile-major index 0..127
    const f16* srcp = &u.Cs[(size_t)c*LDC + half*64];
    f16* dst;
    if (z == 2) {
      int bb = row0 >> 11, ss0 = (row0 & (S_-1)) + half*64;
      dst = vT + ((size_t)bb*D_ + col0 + c)*S_ + ss0;
    } else {
      dst = out + (size_t)(row0 + c)*D_ + col0 + half*64;
    }
#pragma unroll
    for (int k=0;k<8;k++)
      *(float4*)(dst + k*8) = *(const float4*)(srcp + k*8);
  }
}

// ---------------- flash attention: head-issued DMA double buffer, plain barriers ----
// Constraints proven over R1-R9: (a) NO inline-asm barriers/waits (3x spill
// reproduction: WRITE_SIZE 335-750MB); (b) NO register state live across MFMA
// clusters (acc already fills the (256,2) budget exactly); (c) plain
// __syncthreads only.  Within those, the one schedule with real DMA cover:
//   4 k-slots (2 pairs).  pair_i slots: even i -> {2,3}, odd i -> {0,1}.
//   head_i (after sync_A): issue DMA(pair_{i+1}) into the idle pair.
//   MFMA phase (64 MFMA) on pair_i + q_i.
//   sync_B; tail: qstage_{i+1} -- the compiler's own vmcnt wait before the q
//   ds_writes drains the DMA too, but by then it is one FULL MFMA phase old
//   => free.  sync_A_{i+1} then drains nothing.  Exposed stall per ko = bare
//   q-load latency only (was + k-DMA residual in R8).
//   tail_15: qstage(next-t0 q_0) + DMA(next-t0 pair_0 -> {2,3}); P aliases
//   slots {0,1} exactly (32KB chunk-swizzled) so the prefetch rides under PV.
// LDS 81920 B (R9 proved 2 blocks/CU at this size).  q uses the xor-chunk
// layout (16KB, no pad).  Keeps R8's setprio + swapped-operand PV epilogue.
#define TQ 128
#define TK 128

__global__ __launch_bounds__(256, 2) void attn_kernel(
    const f16* __restrict__ q16, const f16* __restrict__ k16,
    const f16* __restrict__ vT, const f16* __restrict__ mix16,
    float* __restrict__ out)
{
  const int b = blockIdx.z;
  const int h = blockIdx.y;
  const int s0 = blockIdx.x * TQ;
  const int tid = threadIdx.x;
  const int lane = tid & 63, wid = tid >> 6;
  const int wm = wid >> 1, wn = wid & 1;
  const int quad = lane >> 4, l16 = lane & 15;

  __shared__ __align__(16) union {
    struct { f16 k[4][TK*BK]; f16 q[TQ*BK]; } s;      // 64KB + 16KB = 81920 B
    f16 P[TQ*TK];                                     // 32KB = slots {0,1} exactly
    struct { f16 _pad[4*TK*BK]; float red_l[2][TQ]; } r;  // red_l aliases q
  } u;

  // P chunk-swizzle: row stride 128 f16 = 16 chunks of 8; chunk ^= row&7.
  // pa-reads (row=l16-varying, col=quad-varying) land 8 lanes/bank-group =
  // the b128-optimal pattern.
#define P_IDX(row, col) ((size_t)((((row)<<4) | ((((col)>>3) ^ ((row)&7))))<<3) | ((col)&7))

  float l_lane[16];
#pragma unroll
  for (int t=0;t<16;t++) l_lane[t] = 0.0f;

  // o_acc[i][j][r] = O[q_row = wm*64+i*16+l16][d = wn*32+j*16+quad*4+r]  (swapped PV)
  float4_ o_acc[4][2];
#pragma unroll
  for (int i=0;i<4;i++)
#pragma unroll
    for (int j=0;j<2;j++) o_acc[i][j] = (float4_)0.0f;

  const f16* qbase = q16 + (size_t)(b*S_ + s0)*D_;
  const f16* kbase = k16 + (size_t)b*S_*D_;
  const f16* mrow  = mix16 + h*D_;
  const f16* vTb   = vT + (size_t)(b*D_ + h*HD_)*S_;

  // stage one k-tile pair (rows t0g, t0g+TK at k-slice ko_) into slots d0,d1
#define STAGE_TO(d0, d1, t0g, ko_) do {                                      \
    const f16* k0g_ = kbase + (size_t)(t0g)*D_ + (ko_);                      \
    const f16* k1g_ = k0g_ + (size_t)TK*D_;                                  \
    _Pragma("unroll")                                                        \
    for (int c_=0; c_<4; c_++) {                                             \
      int slot_ = (wid*4+c_)*64 + lane;                                      \
      int r_ = slot_ >> 3;                                                   \
      int gc_ = (slot_ & 7) ^ (r_ & 7);                                      \
      gl_lds16(k0g_ + (size_t)r_*D_ + gc_*8, (d0) + (size_t)(wid*4+c_)*64*8); \
      gl_lds16(k1g_ + (size_t)r_*D_ + gc_*8, (d1) + (size_t)(wid*4+c_)*64*8); \
    } } while (0)

  // q staging: transient VALU (load, fuse mix, ds_write to xor-chunk layout)
#define QSTAGE(ko_) do {                                                     \
    _Pragma("unroll")                                                        \
    for (int it_=0; it_<4; it_++) {                                          \
      int c_ = it_*256 + tid; int r_ = c_>>3; int cc_ = c_&7;                \
      half8 qv_ = *(const half8*)&qbase[(size_t)r_*D_ + (ko_) + cc_*8];      \
      half8 mv_ = *(const half8*)&mrow[(ko_) + cc_*8];                       \
      *(half8*)&u.s.q[(size_t)(((r_<<3) | (cc_ ^ (r_&7))) << 3)] = qv_ * mv_; \
    } } while (0)

  // kernel prologue: pair_0 -> slots {2,3}; q_0
  STAGE_TO(u.s.k[2], u.s.k[3], 0, 0);
  QSTAGE(0);

  for (int t0 = 0; t0 < S_; t0 += 2*TK) {
    const bool has_next = (t0 + 2*TK < S_);

    float4_ sacc[2][4][4];
#pragma unroll
    for (int tt=0;tt<2;tt++)
#pragma unroll
      for (int i=0;i<4;i++)
#pragma unroll
        for (int j=0;j<4;j++) sacc[tt][i][j] = (float4_)0.0f;

    for (int ko_i = 0; ko_i < D_/BK; ko_i++) {
      const int ko = ko_i * BK;

      __syncthreads();   // sync_A: DMA(pair_i) is a full phase old -> free drain

      // head: issue next pair into the idle slots (opposite parity)
      if (ko_i < D_/BK - 1) {
        if (ko_i & 1) STAGE_TO(u.s.k[2], u.s.k[3], t0, ko + BK);
        else          STAGE_TO(u.s.k[0], u.s.k[1], t0, ko + BK);
      }

      const f16* kA = (ko_i & 1) ? u.s.k[0] : u.s.k[2];
      const f16* kB = (ko_i & 1) ? u.s.k[1] : u.s.k[3];

      __builtin_amdgcn_s_setprio(1);
#pragma unroll
      for (int kk2=0; kk2<2; kk2++) {
        const int ck = kk2*4 + quad;
        half8 a[4];
#pragma unroll
        for (int i=0;i<4;i++) {
          int rr = wm*64 + i*16 + l16;
          a[i] = *(const half8*)&u.s.q[(size_t)(((rr<<3) | (ck ^ (rr&7))) << 3)];
        }
#pragma unroll
        for (int tt=0;tt<2;tt++) {
          const f16* kb = tt ? kB : kA;
          half8 bf[4];
#pragma unroll
          for (int j=0;j<4;j++) {
            int rr = wn*64 + j*16 + l16;
            bf[j] = *(const half8*)&kb[(size_t)(((rr<<3) | (ck ^ (rr&7))) << 3)];
          }
#pragma unroll
          for (int i=0;i<4;i++)
#pragma unroll
            for (int j=0;j<4;j++)
              sacc[tt][i][j] = __builtin_amdgcn_mfma_f32_16x16x32_f16(a[i], bf[j], sacc[tt][i][j], 0,0,0);
        }
      }
      __builtin_amdgcn_s_setprio(0);

      __syncthreads();   // sync_B: reads of pair_i & q_i retired

      // tail: q for the next slice (compiler's vmcnt wait here also drains the
      // head-issued DMA -- already a full MFMA phase old, so free)
      if (ko_i < D_/BK - 1) {
        QSTAGE(ko + BK);
      } else if (has_next) {
        QSTAGE(0);                                     // next-t0 q_0
        STAGE_TO(u.s.k[2], u.s.k[3], t0 + 2*TK, 0);    // next-t0 pair_0 (rides PV)
      }
    }

    // ---- per sub-tile: P = exp2(S), l partials, P->LDS (slots 0-1), PV ----
#pragma unroll
    for (int tt=0;tt<2;tt++) {
#pragma unroll
      for (int i=0;i<4;i++)
#pragma unroll
        for (int j=0;j<4;j++)
#pragma unroll
          for (int r=0;r<4;r++) {
            float p = __builtin_exp2f(sacc[tt][i][j][r]);
            l_lane[i*4+r] += p;
            u.P[P_IDX(wm*64+i*16+quad*4+r, wn*64+j*16+l16)] = (f16)p;
          }

      // prefetch PV fragments (latency hides under barrier; transient regs)
      half8 vb[8];
#pragma unroll
      for (int ki=0; ki<4; ki++)
#pragma unroll
        for (int j=0; j<2; j++) {
          int ch = wn*32 + j*16 + l16;
          vb[ki*2+j] = *(const half8*)&vTb[(size_t)ch*S_ + t0 + tt*TK + ki*32 + quad*8];
        }

      __syncthreads();

      __builtin_amdgcn_s_setprio(1);
#pragma unroll
      for (int ki=0; ki<4; ki++) {
        half8 pa[4];
#pragma unroll
        for (int i=0;i<4;i++)
          pa[i] = *(const half8*)&u.P[P_IDX(wm*64+i*16+l16, ki*32+quad*8)];
#pragma unroll
        for (int i=0;i<4;i++)
#pragma unroll
          for (int j=0;j<2;j++)
            o_acc[i][j] = __builtin_amdgcn_mfma_f32_16x16x32_f16(vb[ki*2+j], pa[i], o_acc[i][j], 0,0,0);
      }
      __builtin_amdgcn_s_setprio(0);
      __syncthreads();   // P reads retired -> tt1 / next-t0 may overwrite
    }
  }

  // ---- epilogue: single l reduction (butterfly over l16, cross-wave via LDS) ----
#pragma unroll
  for (int d=1; d<16; d<<=1)
#pragma unroll
    for (int t=0;t<16;t++) l_lane[t] += __shfl_xor(l_lane[t], d);
  if (l16 == 0) {
#pragma unroll
    for (int i=0;i<4;i++)
#pragma unroll
      for (int r=0;r<4;r++)
        u.r.red_l[wn][wm*64+i*16+quad*4+r] = l_lane[i*4+r];
  }
  __syncthreads();

  // swapped-PV epilogue: lane holds 4 consecutive d for q_row = wm*64+i*16+l16
#pragma unroll
  for (int i=0;i<4;i++) {
    int row = wm*64 + i*16 + l16;
    float linv = 1.0f / (u.r.red_l[0][row] + u.r.red_l[1][row]);
#pragma unroll
    for (int j=0;j<2;j++) {
      float4 v4;
      v4.x = o_acc[i][j][0] * linv;
      v4.y = o_acc[i][j][1] * linv;
      v4.z = o_acc[i][j][2] * linv;
      v4.w = o_acc[i][j][3] * linv;
      *(float4*)&out[(size_t)(b*S_ + s0 + row)*D_ + h*HD_ + wn*32 + j*16 + quad*4] = v4;
    }
  }
}

// ---------------- launch ----------------
extern "C" void kernel_launch(void* const* d_in, const int* in_sizes, int n_in,
                              void* d_out, int out_size, void* d_ws, size_t ws_size,
                              hipStream_t stream) {
  (void)in_sizes; (void)n_in; (void)out_size; (void)ws_size;
  const float* hs  = (const float*)d_in[0];
  const float* Wq  = (const float*)d_in[1];
  const float* Wk  = (const float*)d_in[2];
  const float* Wv  = (const float*)d_in[3];
  const float* bv  = (const float*)d_in[4];
  const float* mix = (const float*)d_in[5];
  float* out = (float*)d_out;

  char* ws = (char*)d_ws;
  f16* hs16  = (f16*)(ws);                       // 8 MB
  f16* w16   = (f16*)(ws + 8388608);             // 6 MB
  f16* mix16 = (f16*)(ws + 14680064);            // 32 KB
  f16* q16   = (f16*)(ws + 14712832);            // 8 MB
  f16* k16   = (f16*)(ws + 23101440);            // 8 MB
  f16* vT    = (f16*)(ws + 31490048);            // 8 MB

  convert_kernel<<<2048, 256, 0, stream>>>(hs, Wq, Wk, Wv, mix,
                                           hs16, w16, w16+N_W, w16+2*N_W, mix16);
  qkv_kernel<<<dim3(D_/BN, (B_*S_)/BM, 3), 256, 0, stream>>>(
      hs16, w16, bv, q16, k16, vT);
  attn_kernel<<<dim3(S_/TQ, H_, B_), 256, 0, stream>>>(
      q16, k16, vT, mix16, out);
}

// Round 11
// 401.400 us; speedup vs baseline: 1.8976x; 1.4724x over previous
//
#include <hip/hip_runtime.h>

#define B_ 2
#define S_ 2048
#define D_ 1024      // D_IN = DKQ = DV = E
#define H_ 16
#define HD_ 64       // DV / H

typedef _Float16 f16;
typedef _Float16 half8 __attribute__((ext_vector_type(8)));
typedef float float4_ __attribute__((ext_vector_type(4)));

#define N_HS (B_*S_*D_)   // 4194304
#define N_W  (D_*D_)      // 1048576
#define N_MIX (H_*D_)     // 16384

__device__ __forceinline__ void gl_lds16(const f16* g, const f16* l) {
  __builtin_amdgcn_global_load_lds(
      (const __attribute__((address_space(1))) void*)g,
      (__attribute__((address_space(3))) void*)l, 16, 0, 0);
}

// ---------------- convert fp32 -> fp16 ----------------
// mixing scaled by (1/sqrt(64)) * (1/ln2): softmax exp becomes a bare exp2
#define MIX_SCALE 0.18033688011112042f

__global__ __launch_bounds__(256) void convert_kernel(
    const float* __restrict__ hs, const float* __restrict__ wq,
    const float* __restrict__ wk, const float* __restrict__ wv,
    const float* __restrict__ mix,
    f16* __restrict__ hs16, f16* __restrict__ wq16, f16* __restrict__ wk16,
    f16* __restrict__ wv16, f16* __restrict__ mix16)
{
  const int total4 = (N_HS + 3*N_W + N_MIX) / 4;
  for (int i4 = blockIdx.x*blockDim.x + threadIdx.x; i4 < total4;
       i4 += gridDim.x*blockDim.x) {
    int i = i4*4;
    const float* src; f16* dst; float scale = 1.0f; int off;
    if (i < N_HS)            { src=hs;  dst=hs16;  off=i; }
    else if (i < N_HS+N_W)   { src=wq;  dst=wq16;  off=i-N_HS; }
    else if (i < N_HS+2*N_W) { src=wk;  dst=wk16;  off=i-N_HS-N_W; }
    else if (i < N_HS+3*N_W) { src=wv;  dst=wv16;  off=i-N_HS-2*N_W; }
    else                     { src=mix; dst=mix16; off=i-N_HS-3*N_W; scale=MIX_SCALE; }
    float4 v = *(const float4*)(src+off);
    dst[off]   = (f16)(v.x*scale);
    dst[off+1] = (f16)(v.y*scale);
    dst[off+2] = (f16)(v.z*scale);
    dst[off+3] = (f16)(v.w*scale);
  }
}

// ---------------- QKV GEMM: 128x128 tiles, DMA staging (m97-style) ----------------
// z==2 (V) adds bias and writes TRANSPOSED: vT[b][ch][t]
// Epilogue: C-tile staged in LDS (transposed for z==2), then coalesced 16B
// float4 stores (R7: killed the vT 2-byte-scatter write amplification).
#define BM 128
#define BN 128
#define BK 64
#define LDC 136   // C-tile pad: keeps 16B alignment (136*2=272=16*17), ~2-way banks

__global__ __launch_bounds__(256, 2) void qkv_kernel(
    const f16* __restrict__ hs16, const f16* __restrict__ w16base,
    const float* __restrict__ bv,
    f16* __restrict__ q16, f16* __restrict__ k16, f16* __restrict__ vT)
{
  const int z = blockIdx.z;
  const f16* W = w16base + (size_t)z * N_W;
  f16* out = (z==0) ? q16 : k16;
  const int mt = blockIdx.y, nt = blockIdx.x;
  const int tid = threadIdx.x;
  const int lane = tid & 63, wid = tid >> 6;
  const int wm = wid >> 1, wn = wid & 1;
  const int quad = lane >> 4, l16 = lane & 15;

  __shared__ __align__(16) union {
    struct { f16 As[BM*BK]; f16 Bs[BN*BK]; } s;  // 32 KB
    f16 Cs[BM*LDC];                              // 34816 B (epilogue staging)
  } u;

  float4_ acc[4][4];
#pragma unroll
  for (int i=0;i<4;i++)
#pragma unroll
    for (int j=0;j<4;j++) acc[i][j] = (float4_)0.0f;

  const int row0 = mt*BM;
  const int col0 = nt*BN;

  for (int ko = 0; ko < D_; ko += BK) {
#pragma unroll
    for (int c=0; c<4; c++) {
      int slot = (wid*4+c)*64 + lane;      // 0..1023 16B chunks
      int r = slot >> 3;
      int gc = (slot & 7) ^ (r & 7);
      gl_lds16(hs16 + (size_t)(row0+r)*D_ + ko + gc*8, u.s.As + (size_t)(wid*4+c)*64*8);
      gl_lds16(W    + (size_t)(col0+r)*D_ + ko + gc*8, u.s.Bs + (size_t)(wid*4+c)*64*8);
    }
    __syncthreads();
#pragma unroll
    for (int kk=0; kk<BK; kk+=32) {
      int ck = (kk >> 3) + quad;
      half8 a[4], b[4];
#pragma unroll
      for (int i=0;i<4;i++) {
        int rr = wm*64 + i*16 + l16;
        a[i] = *(const half8*)&u.s.As[(size_t)(((rr<<3) | (ck ^ (rr&7))) << 3)];
      }
#pragma unroll
      for (int j=0;j<4;j++) {
        int rr = wn*64 + j*16 + l16;
        b[j] = *(const half8*)&u.s.Bs[(size_t)(((rr<<3) | (ck ^ (rr&7))) << 3)];
      }
#pragma unroll
      for (int i=0;i<4;i++)
#pragma unroll
        for (int j=0;j<4;j++)
          acc[i][j] = __builtin_amdgcn_mfma_f32_16x16x32_f16(a[i], b[j], acc[i][j], 0,0,0);
    }
    __syncthreads();
  }

  // ---- epilogue: LDS-staged coalesced stores ----
#pragma unroll
  for (int i=0;i<4;i++) {
#pragma unroll
    for (int j=0;j<4;j++) {
      int c = wn*64 + j*16 + l16;
      float bias = (z==2) ? bv[col0 + c] : 0.0f;
#pragma unroll
      for (int r=0;r<4;r++) {
        int rr = wm*64 + i*16 + quad*4 + r;
        f16 val = (f16)(acc[i][j][r] + bias);
        u.Cs[(z==2) ? ((size_t)c*LDC + rr) : ((size_t)rr*LDC + c)] = val;
      }
    }
  }
  __syncthreads();
  {
    const int c = tid >> 1, half = tid & 1;   // c: tile-major index 0..127
    const f16* srcp = &u.Cs[(size_t)c*LDC + half*64];
    f16* dst;
    if (z == 2) {
      int bb = row0 >> 11, ss0 = (row0 & (S_-1)) + half*64;
      dst = vT + ((size_t)bb*D_ + col0 + c)*S_ + ss0;
    } else {
      dst = out + (size_t)(row0 + c)*D_ + col0 + half*64;
    }
#pragma unroll
    for (int k=0;k<8;k++)
      *(float4*)(dst + k*8) = *(const float4*)(srcp + k*8);
  }
}

// ---------------- flash attention (R8 structure + xor-chunk q layout) ----------------
// R8 core is the verified fixed point: q VALU staging between k-DMA issue and
// barrier A covers DMA latency; any structural perturbation spills (R1-R4,
// R9, R10: WRITE_SIZE 221-750MB scratch).  Round-11 change is index-arithmetic
// ONLY: q staged in the xor-chunk layout (same scheme as k-tiles).  R8's
// padded q[128][72] ds_write was an 8-way bank conflict (lane (r,c) -> bank
// group (4r+4c) mod 32); chunk layout is conflict-free on write, 2-way (free)
// on read.  Counter evidence: padded-q rounds show SQ_LDS_BANK_CONFLICT
// 1.049e7, chunk-q rounds 2.1e6.
#define TQ 128
#define TK 128
#define LDP 136

__global__ __launch_bounds__(256, 2) void attn_kernel(
    const f16* __restrict__ q16, const f16* __restrict__ k16,
    const f16* __restrict__ vT, const f16* __restrict__ mix16,
    float* __restrict__ out)
{
  const int b = blockIdx.z;
  const int h = blockIdx.y;
  const int s0 = blockIdx.x * TQ;
  const int tid = threadIdx.x;
  const int lane = tid & 63, wid = tid >> 6;
  const int wm = wid >> 1, wn = wid & 1;
  const int quad = lane >> 4, l16 = lane & 15;

  // staging: q (VALU, mix fused, xor-chunk) + TWO k tiles (DMA, xor-chunk)
  __shared__ __align__(16) union {
    struct { f16 q[TQ*BK]; f16 k0[TK*BK]; f16 k1[TK*BK]; } s1;  // 49152 B
    f16 P[TQ][LDP];                                             // 34816 B
  } u;
  __shared__ __align__(16) float red_l[2][TQ];

  // per-lane l partials: 16 rows/lane (row = wm*64+i*16+quad*4+r)
  float l_lane[16];
#pragma unroll
  for (int t=0;t<16;t++) l_lane[t] = 0.0f;

  // o_acc[i][j][r] = O[q_row = wm*64+i*16+l16][d = wn*32+j*16+quad*4+r]  (swapped PV)
  float4_ o_acc[4][2];
#pragma unroll
  for (int i=0;i<4;i++)
#pragma unroll
    for (int j=0;j<2;j++) o_acc[i][j] = (float4_)0.0f;

  const f16* qbase = q16 + (size_t)(b*S_ + s0)*D_;
  const f16* kbase = k16 + (size_t)b*S_*D_;
  const f16* mrow  = mix16 + h*D_;
  const f16* vTb   = vT + (size_t)(b*D_ + h*HD_)*S_;

  for (int t0 = 0; t0 < S_; t0 += 2*TK) {
    // ---- S[2 tiles] = (q*mix) @ k^T over K=1024 ----
    float4_ sacc[2][4][4];
#pragma unroll
    for (int tt=0;tt<2;tt++)
#pragma unroll
      for (int i=0;i<4;i++)
#pragma unroll
        for (int j=0;j<4;j++) sacc[tt][i][j] = (float4_)0.0f;

    for (int ko = 0; ko < D_; ko += BK) {
      const f16* k0g = kbase + (size_t)t0*D_ + ko;
      const f16* k1g = k0g + (size_t)TK*D_;
#pragma unroll
      for (int c=0; c<4; c++) {
        int slot = (wid*4+c)*64 + lane;
        int r = slot >> 3;
        int gc = (slot & 7) ^ (r & 7);
        gl_lds16(k0g + (size_t)r*D_ + gc*8, u.s1.k0 + (size_t)(wid*4+c)*64*8);
        gl_lds16(k1g + (size_t)r*D_ + gc*8, u.s1.k1 + (size_t)(wid*4+c)*64*8);
      }
      // q-tile: VALU staging with mix fused, xor-chunk layout (conflict-free)
#pragma unroll
      for (int it=0; it<4; it++) {
        int c = it*256 + tid;
        int r = c >> 3, cc = c & 7;
        half8 qv = *(const half8*)&qbase[(size_t)r*D_ + ko + cc*8];
        half8 mv = *(const half8*)&mrow[ko + cc*8];
        *(half8*)&u.s1.q[(size_t)(((r<<3) | (cc ^ (r&7))) << 3)] = qv * mv;
      }
      __syncthreads();
      __builtin_amdgcn_s_setprio(1);
#pragma unroll
      for (int kk=0; kk<BK; kk+=32) {
        const int ck = (kk >> 3) + quad;
        half8 a[4];
#pragma unroll
        for (int i=0;i<4;i++) {
          int rr = wm*64 + i*16 + l16;
          a[i] = *(const half8*)&u.s1.q[(size_t)(((rr<<3) | (ck ^ (rr&7))) << 3)];
        }
#pragma unroll
        for (int tt=0;tt<2;tt++) {
          const f16* kb = tt ? u.s1.k1 : u.s1.k0;
          half8 bf[4];
#pragma unroll
          for (int j=0;j<4;j++) {
            int rr = wn*64 + j*16 + l16;
            bf[j] = *(const half8*)&kb[(size_t)(((rr<<3) | (ck ^ (rr&7))) << 3)];
          }
#pragma unroll
          for (int i=0;i<4;i++)
#pragma unroll
            for (int j=0;j<4;j++)
              sacc[tt][i][j] = __builtin_amdgcn_mfma_f32_16x16x32_f16(a[i], bf[j], sacc[tt][i][j], 0,0,0);
        }
      }
      __builtin_amdgcn_s_setprio(0);
      __syncthreads();
    }

    // ---- per sub-tile: P = exp2(S), l partials, P->LDS, PV (swapped) ----
#pragma unroll
    for (int tt=0;tt<2;tt++) {
#pragma unroll
      for (int i=0;i<4;i++)
#pragma unroll
        for (int j=0;j<4;j++)
#pragma unroll
          for (int r=0;r<4;r++) {
            float p = __builtin_exp2f(sacc[tt][i][j][r]);
            l_lane[i*4+r] += p;
            u.P[wm*64+i*16+quad*4+r][wn*64+j*16+l16] = (f16)p;
          }

      // prefetch PV fragments (latency hides under barrier)
      half8 vb[8];
#pragma unroll
      for (int ki=0; ki<4; ki++)
#pragma unroll
        for (int j=0; j<2; j++) {
          int ch = wn*32 + j*16 + l16;
          vb[ki*2+j] = *(const half8*)&vTb[(size_t)ch*S_ + t0 + tt*TK + ki*32 + quad*8];
        }

      __syncthreads();

      __builtin_amdgcn_s_setprio(1);
#pragma unroll
      for (int ki=0; ki<4; ki++) {
        half8 pa[4];
#pragma unroll
        for (int i=0;i<4;i++) pa[i] = *(const half8*)&u.P[wm*64+i*16+l16][ki*32+quad*8];
#pragma unroll
        for (int i=0;i<4;i++)
#pragma unroll
          for (int j=0;j<2;j++)
            o_acc[i][j] = __builtin_amdgcn_mfma_f32_16x16x32_f16(vb[ki*2+j], pa[i], o_acc[i][j], 0,0,0);
      }
      __builtin_amdgcn_s_setprio(0);
      __syncthreads();
    }
  }

  // ---- epilogue: single l reduction (butterfly over l16, cross-wave via LDS) ----
#pragma unroll
  for (int d=1; d<16; d<<=1)
#pragma unroll
    for (int t=0;t<16;t++) l_lane[t] += __shfl_xor(l_lane[t], d);
  if (l16 == 0) {
#pragma unroll
    for (int i=0;i<4;i++)
#pragma unroll
      for (int r=0;r<4;r++)
        red_l[wn][wm*64+i*16+quad*4+r] = l_lane[i*4+r];
  }
  __syncthreads();

  // swapped-PV epilogue: lane holds 4 consecutive d for q_row = wm*64+i*16+l16
#pragma unroll
  for (int i=0;i<4;i++) {
    int row = wm*64 + i*16 + l16;
    float linv = 1.0f / (red_l[0][row] + red_l[1][row]);
#pragma unroll
    for (int j=0;j<2;j++) {
      float4 v4;
      v4.x = o_acc[i][j][0] * linv;
      v4.y = o_acc[i][j][1] * linv;
      v4.z = o_acc[i][j][2] * linv;
      v4.w = o_acc[i][j][3] * linv;
      *(float4*)&out[(size_t)(b*S_ + s0 + row)*D_ + h*HD_ + wn*32 + j*16 + quad*4] = v4;
    }
  }
}

// ---------------- launch ----------------
extern "C" void kernel_launch(void* const* d_in, const int* in_sizes, int n_in,
                              void* d_out, int out_size, void* d_ws, size_t ws_size,
                              hipStream_t stream) {
  (void)in_sizes; (void)n_in; (void)out_size; (void)ws_size;
  const float* hs  = (const float*)d_in[0];
  const float* Wq  = (const float*)d_in[1];
  const float* Wk  = (const float*)d_in[2];
  const float* Wv  = (const float*)d_in[3];
  const float* bv  = (const float*)d_in[4];
  const float* mix = (const float*)d_in[5];
  float* out = (float*)d_out;

  char* ws = (char*)d_ws;
  f16* hs16  = (f16*)(ws);                       // 8 MB
  f16* w16   = (f16*)(ws + 8388608);             // 6 MB
  f16* mix16 = (f16*)(ws + 14680064);            // 32 KB
  f16* q16   = (f16*)(ws + 14712832);            // 8 MB
  f16* k16   = (f16*)(ws + 23101440);            // 8 MB
  f16* vT    = (f16*)(ws + 31490048);            // 8 MB

  convert_kernel<<<2048, 256, 0, stream>>>(hs, Wq, Wk, Wv, mix,
                                           hs16, w16, w16+N_W, w16+2*N_W, mix16);
  qkv_kernel<<<dim3(D_/BN, (B_*S_)/BM, 3), 256, 0, stream>>>(
      hs16, w16, bv, q16, k16, vT);
  attn_kernel<<<dim3(S_/TQ, H_, B_), 256, 0, stream>>>(
      q16, k16, vT, mix16, out);
}